// Round 1
// 232.781 us; speedup vs baseline: 1.0080x; 1.0080x over previous
//
#include <hip/hip_runtime.h>

// CML1D: 15-step coupled map lattice, fp32, rows=2048, L=16384.
//   mapped = R*g*(1-g);  g' = c0*mapped[i-1] + c1*mapped[i] + c2*mapped[i+1] + BETA*d
//   c0=(1-B)E*K0, c1=(1-B)(1-E)+(1-B)E*K1, c2=(1-B)E*K2   (circular)
// out = clip(g, 1e-4, 1-1e-4) after 15 steps.
//
// R4: VALU-diet + stall-hiding on top of R3's barrier-free wave ghost zones.
//   - Fold R into the tap coefficients: mapped = R*mh with mh = g - g^2 =
//     fmaf(-g,g,g) (ONE op instead of two), taps d{0,1,2} = R*c{0,1,2}.
//     4 VALU/cell/step instead of 5 (~22% cut in the dominant pipe).
//   - Boundary cells (i=0, i=CE-1) are updated LAST: issue the two
//     ds_bpermute ghost exchanges first (addresses precomputed once),
//     compute the 15 interior cells while they're in flight -> the
//     lgkmcnt wait is buried under ~60 VALU instructions per step.
//   - Everything else (per-wave private LDS slots, coalesced float4 I/O,
//     GHOST=32 > 15 steps of edge garbage, no __syncthreads) unchanged.

constexpr float Rc    = 3.9f;
constexpr float EPSc  = 0.3f;
constexpr float BETAc = 0.15f;
constexpr int   STEPS = 15;
constexpr int   L     = 16384;
constexpr int   CE    = 17;           // cells per lane (extended)
constexpr int   SEG   = 1024;         // valid cells per wave
constexpr int   GHOST = 32;           // ghost cells per side
constexpr int   EXT   = SEG + 2*GHOST;  // 1088
constexpr int   TPB   = 256;
constexpr int   WPB   = TPB / 64;     // 4 waves per block

__global__ __launch_bounds__(TPB)
void cml1d_kernel(const float* __restrict__ drive,
                  const float* __restrict__ K,
                  float* __restrict__ out) {
    __shared__ float lds[WPB][EXT];   // 4*1088*4 = 17408 B, per-wave private slots

    const int lane = threadIdx.x & 63;
    const int wv   = threadIdx.x >> 6;
    const int gw   = blockIdx.x * WPB + wv;
    const int row  = gw >> 4;                 // 16 segments per row
    const int seg  = gw & 15;
    const size_t rowbase = (size_t)row * L;
    const int wbase = seg * SEG - GHOST;      // extended window start (may be <0)

    // ---- coalesced load: 272 float4 per wave (rounds of 64 lanes) -> LDS ----
    #pragma unroll
    for (int j = 0; j < 5; ++j) {
        int f = j * 64 + lane;
        if (f < EXT / 4) {
            int e   = wbase + f * 4;          // multiple of 4; window wrap is
            int idx = e & (L - 1);            // also multiple of 4 -> float4 safe
            float4 v = *reinterpret_cast<const float4*>(drive + rowbase + idx);
            *reinterpret_cast<float4*>(&lds[wv][f * 4]) = v;
        }
    }
    __builtin_amdgcn_wave_barrier();  // keep ds_write before ds_read in program order

    const float K0 = K[0], K1 = K[1], K2 = K[2];
    const float A  = (1.0f - BETAc) * (1.0f - EPSc);
    const float B  = (1.0f - BETAc) * EPSc;
    // mapped = R*mh, mh = g - g^2 = fmaf(-g,g,g): fold R into the taps.
    const float d0 = Rc * (B * K0);
    const float d1 = Rc * (A + B * K1);
    const float d2 = Rc * (B * K2);

    // ---- LDS -> registers: lane's 17 contiguous cells (stride 17: 2-way, free)
    float g[CE], bd[CE];
    #pragma unroll
    for (int i = 0; i < CE; ++i) {
        float v = lds[wv][lane * CE + i];
        g[i]  = v;
        bd[i] = BETAc * v;
    }

    // ghost-exchange bpermute addresses, hoisted out of the step loop.
    // lane 0's left / lane 63's right pull wrapped garbage -> ghost region only.
    const int addrL = ((lane - 1) & 63) << 2;
    const int addrR = ((lane + 1) & 63) << 2;

    // ---- 15 steps, register-only, no barriers ----
    for (int s = 0; s < STEPS; ++s) {
        // boundary mh first, shuffles issued immediately...
        float mh0  = fmaf(-g[0],      g[0],      g[0]);        // g - g^2
        float mhT  = fmaf(-g[CE - 1], g[CE - 1], g[CE - 1]);
        float mleft  = __int_as_float(
            __builtin_amdgcn_ds_bpermute(addrL, __float_as_int(mhT)));
        float mright = __int_as_float(
            __builtin_amdgcn_ds_bpermute(addrR, __float_as_int(mh0)));

        // ...interior cells computed while the bpermutes are in flight.
        float mprev = mh0;
        float mcur  = fmaf(-g[1], g[1], g[1]);
        const float m1s = mcur;                 // mh[1], needed for i=0 later
        float mTs = mcur;                       // becomes mh[CE-2]
        #pragma unroll
        for (int i = 1; i < CE - 1; ++i) {
            float mnext;
            if (i == CE - 2) { mnext = mhT; mTs = mcur; }
            else {
                float gv = g[i + 1];
                mnext = fmaf(-gv, gv, gv);
            }
            g[i] = fmaf(d0, mprev, fmaf(d1, mcur, fmaf(d2, mnext, bd[i])));
            mprev = mcur;
            mcur  = mnext;
        }
        // boundary cells last: lgkmcnt wait lands here, fully hidden.
        g[0]      = fmaf(d0, mleft, fmaf(d1, mh0, fmaf(d2, m1s,    bd[0])));
        g[CE - 1] = fmaf(d0, mTs,   fmaf(d1, mhT, fmaf(d2, mright, bd[CE - 1])));
    }

    // ---- registers -> LDS -> coalesced float4 stores of valid middle 1024 ----
    __builtin_amdgcn_wave_barrier();
    #pragma unroll
    for (int i = 0; i < CE; ++i) lds[wv][lane * CE + i] = g[i];
    __builtin_amdgcn_wave_barrier();

    const float lo = 0.0001f;
    const float hi = 0.9999f;   // float(1.0 - 0.0001)
    #pragma unroll
    for (int j = 0; j < 4; ++j) {
        int f = j * 64 + lane;                    // 256 float4 = 1024 floats
        float4 v = *reinterpret_cast<float4*>(&lds[wv][GHOST + f * 4]);
        v.x = fminf(fmaxf(v.x, lo), hi);
        v.y = fminf(fmaxf(v.y, lo), hi);
        v.z = fminf(fmaxf(v.z, lo), hi);
        v.w = fminf(fmaxf(v.w, lo), hi);
        *reinterpret_cast<float4*>(out + rowbase + seg * SEG + f * 4) = v;
    }
}

extern "C" void kernel_launch(void* const* d_in, const int* in_sizes, int n_in,
                              void* d_out, int out_size, void* d_ws, size_t ws_size,
                              hipStream_t stream) {
    const float* drive = (const float*)d_in[0];
    const float* K     = (const float*)d_in[1];
    float* out         = (float*)d_out;
    const int rows   = in_sizes[0] / L;           // 2048
    const int gwaves = rows * (L / SEG);          // 32768
    const int blocks = gwaves / WPB;              // 8192
    cml1d_kernel<<<dim3(blocks), dim3(TPB), 0, stream>>>(drive, K, out);
}